// Round 8
// baseline (1094.157 us; speedup 1.0000x reference)
//
#include <hip/hip_runtime.h>

#define BATCH 64
#define SEQT  2048
#define DIM   256   // INPUT_SIZE
#define HID   256   // HIDDEN_SIZE

typedef _Float16 half_t;
typedef _Float16 half2_t __attribute__((ext_vector_type(2)));
typedef _Float16 half4_t __attribute__((ext_vector_type(4)));
typedef _Float16 half8_t __attribute__((ext_vector_type(8)));
typedef float    float4_t __attribute__((ext_vector_type(4)));

__device__ __forceinline__ half8_t cvt8(float4_t a, float4_t b) {
  half8_t r;
  r[0] = (half_t)a[0]; r[1] = (half_t)a[1]; r[2] = (half_t)a[2]; r[3] = (half_t)a[3];
  r[4] = (half_t)b[0]; r[5] = (half_t)b[1]; r[6] = (half_t)b[2]; r[7] = (half_t)b[3];
  return r;
}
// extract half2 #c from a half8 (c MUST be a parse-time literal)
#define H2X(v, c) __builtin_shufflevector((v), (v), 2*(c), 2*(c)+1)

// DPP lane-move (pure VALU).
// 0xB1 = quad_perm lane^1; 0x4E = quad_perm lane^2;
// 0x141 = row_half_mirror (XOR7 within 8); 0x140 = row_mirror (XOR15 within 16)
template<int CTRL>
__device__ __forceinline__ float dpp_mov(float a) {
  int t = __builtin_amdgcn_mov_dpp(__builtin_bit_cast(int, a), CTRL, 0xF, 0xF, true);
  return __builtin_bit_cast(float, t);
}

// ---------------------------------------------------------------------------
// Kernel 0: convert W_xh fp32 -> f16 into d_ws (one-time, trivial).
// ---------------------------------------------------------------------------
__global__ __launch_bounds__(256) void cvt_w_kernel(
    const float* __restrict__ W, half_t* __restrict__ Wh)
{
  const int i = (blockIdx.x * 256 + threadIdx.x) * 4;
  float4_t v = *(const float4_t*)(W + i);
  half4_t o; o[0]=(half_t)v[0]; o[1]=(half_t)v[1]; o[2]=(half_t)v[2]; o[3]=(half_t)v[3];
  *(half4_t*)(Wh + i) = o;
}

// ---------------------------------------------------------------------------
// Kernel 1 v2 (B-stationary): P[m,n] = sum_k x[m,k]*Wxh[n,k] + bh[n] -> out.
// 1024 blocks x 128 rows.  Each wave owns 4 n-tiles; their B-fragments
// (4x8 half8 = 128 VGPR) are loaded ONCE, then 8 M-tiles stream through.
// ---------------------------------------------------------------------------
__global__ __launch_bounds__(256) void xproj_f16_v2(
    const float* __restrict__ x, const half_t* __restrict__ Wh,
    const float* __restrict__ bh, float* __restrict__ out)
{
  const int lane = threadIdx.x & 63;
  const int wave = threadIdx.x >> 6;
  const int r16  = lane & 15;
  const int kg   = lane >> 4;
  const long m0  = (long)blockIdx.x * 128;

  half8_t bfr[4][8];
  float bb[4];
  #pragma unroll
  for (int q = 0; q < 4; ++q) {
    const int nt = wave * 4 + q;
    const half_t* wr = Wh + (nt * 16 + r16) * (long)DIM + kg * 8;
    #pragma unroll
    for (int kf = 0; kf < 8; ++kf)
      bfr[q][kf] = *(const half8_t*)(wr + kf * 32);
    bb[q] = bh[nt * 16 + r16];
  }

  #pragma unroll 1
  for (int mi = 0; mi < 8; ++mi) {
    const long mrow = m0 + mi * 16;
    half8_t a[8];
    const float* xr = x + (mrow + r16) * (long)DIM + kg * 8;
    #pragma unroll
    for (int kf = 0; kf < 8; ++kf) {
      float4_t x0 = *(const float4_t*)(xr + kf * 32);
      float4_t x1 = *(const float4_t*)(xr + kf * 32 + 4);
      a[kf] = cvt8(x0, x1);
    }
    #pragma unroll
    for (int q = 0; q < 4; ++q) {
      float4_t acc = {bb[q], bb[q], bb[q], bb[q]};
      #pragma unroll
      for (int kf = 0; kf < 8; ++kf)
        acc = __builtin_amdgcn_mfma_f32_16x16x32_f16(a[kf], bfr[q][kf], acc, 0, 0, 0);
      float* op = out + (mrow + kg * 4) * (long)HID + (wave * 4 + q) * 16 + r16;
      #pragma unroll
      for (int r = 0; r < 4; ++r) op[(long)r * HID] = acc[r];
    }
  }
}

// Fallback (fp32 weights) if ws can't hold f16 weights.
__global__ __launch_bounds__(256) void xproj_kernel(
    const float* __restrict__ x, const float* __restrict__ Wxh,
    const float* __restrict__ bh, float* __restrict__ out)
{
  const int lane = threadIdx.x & 63;
  const int wave = threadIdx.x >> 6;
  const int r16  = lane & 15;
  const int kg   = lane >> 4;
  const long m0  = (long)blockIdx.x * 64 + wave * 16;

  half8_t a[8];
  const float* xr = x + (m0 + r16) * (long)DIM + kg * 8;
  #pragma unroll
  for (int kf = 0; kf < 8; ++kf) {
    float4_t x0 = *(const float4_t*)(xr + kf * 32);
    float4_t x1 = *(const float4_t*)(xr + kf * 32 + 4);
    a[kf] = cvt8(x0, x1);
  }
  for (int nt = 0; nt < 16; ++nt) {
    const float* wr = Wxh + (nt * 16 + r16) * (long)DIM + kg * 8;
    float bb = bh[nt * 16 + r16];
    float4_t acc = {bb, bb, bb, bb};
    #pragma unroll
    for (int kf = 0; kf < 8; ++kf) {
      float4_t w0 = *(const float4_t*)(wr + kf * 32);
      float4_t w1 = *(const float4_t*)(wr + kf * 32 + 4);
      acc = __builtin_amdgcn_mfma_f32_16x16x32_f16(a[kf], cvt8(w0, w1), acc, 0, 0, 0);
    }
    float* op = out + (m0 + kg * 4) * (long)HID + nt * 16 + r16;
    #pragma unroll
    for (int r = 0; r < 4; ++r) op[(long)r * HID] = acc[r];
  }
}

// ---------------------------------------------------------------------------
// Kernel 2 (v7b): h_t = relu(xp_t + W_hh h_{t-1}).  One block per chain,
// 512 threads = 8 waves.  Per-lane K-width 16 (halves LDS delivery vs v6):
//   g = l & 15            K-chunk of 16 columns [16g, 16g+16)
//   o = w*4 + (l>>4)      output octet: rows [8o, 8o+8)
// Thread: 8 partials over its 16-wide chunk = 64 fdot2; h-read = 32 B/lane
// (2x ds_read_b128) -> 16 reads/step/CU: LDS drain ~192 cyc.
// Reduce-scatter over the 16 chunks (lane bits 0..3), 4 DPP stages:
//   A: XOR15 (row_mirror 0x140),      keep idx bit2 == l.bit3
//   B: XOR7  (row_half_mirror 0x141), keep idx bit1 == l.bit2
//   C: XOR2  (quad_perm 0x4E),        keep idx bit0 == l.bit1
//   D: XOR1  (quad_perm 0xB1),        all-reduce (lanes {l,l^1} share)
// -> lanes {l,l^1} own output jown = 8o + ((l>>1)&7); dup stores benign.
// Branch-free epilogue; xp prefetch 4 deep at uniform clamped addresses ->
// deterministic counted vmcnt; lgkmcnt-only barrier keeps globals in flight.
// LDS h layout: chunk g at byte 48g (32 B data + 16 B pad): read banks
// 12g mod 32 -> exactly 2-way aliasing (free).
// ---------------------------------------------------------------------------
#define RNN_BAR() asm volatile("s_waitcnt lgkmcnt(0)\n\ts_barrier" ::: "memory")

// one K-pair (literal c) of the 16 fdot2s across the 8 accumulators
#define RNN_DOTC(c)                                                            \
    a0 = __builtin_amdgcn_fdot2(H2X(w8[0][0], c), H2X(hv0, c), a0, false);     \
    a1 = __builtin_amdgcn_fdot2(H2X(w8[1][0], c), H2X(hv0, c), a1, false);     \
    a2 = __builtin_amdgcn_fdot2(H2X(w8[2][0], c), H2X(hv0, c), a2, false);     \
    a3 = __builtin_amdgcn_fdot2(H2X(w8[3][0], c), H2X(hv0, c), a3, false);     \
    a4 = __builtin_amdgcn_fdot2(H2X(w8[4][0], c), H2X(hv0, c), a4, false);     \
    a5 = __builtin_amdgcn_fdot2(H2X(w8[5][0], c), H2X(hv0, c), a5, false);     \
    a6 = __builtin_amdgcn_fdot2(H2X(w8[6][0], c), H2X(hv0, c), a6, false);     \
    a7 = __builtin_amdgcn_fdot2(H2X(w8[7][0], c), H2X(hv0, c), a7, false);     \
    a0 = __builtin_amdgcn_fdot2(H2X(w8[0][1], c), H2X(hv1, c), a0, false);     \
    a1 = __builtin_amdgcn_fdot2(H2X(w8[1][1], c), H2X(hv1, c), a1, false);     \
    a2 = __builtin_amdgcn_fdot2(H2X(w8[2][1], c), H2X(hv1, c), a2, false);     \
    a3 = __builtin_amdgcn_fdot2(H2X(w8[3][1], c), H2X(hv1, c), a3, false);     \
    a4 = __builtin_amdgcn_fdot2(H2X(w8[4][1], c), H2X(hv1, c), a4, false);     \
    a5 = __builtin_amdgcn_fdot2(H2X(w8[5][1], c), H2X(hv1, c), a5, false);     \
    a6 = __builtin_amdgcn_fdot2(H2X(w8[6][1], c), H2X(hv1, c), a6, false);     \
    a7 = __builtin_amdgcn_fdot2(H2X(w8[7][1], c), H2X(hv1, c), a7, false);

#define RNN_STEP(U, XQ)                                                        \
  {                                                                            \
    const int t = t4 + (U);                                                    \
    const int tp = (t + 4 < T) ? (t + 4) : (T - 1);                            \
    float xnew = outp[(long)tp * HID];                                         \
    half8_t hv0 = *(const half8_t*)(hraw[(U) & 1] + rb);                       \
    half8_t hv1 = *(const half8_t*)(hraw[(U) & 1] + rb + 16);                  \
    float a0=0.f,a1=0.f,a2=0.f,a3=0.f,a4=0.f,a5=0.f,a6=0.f,a7=0.f;             \
    RNN_DOTC(0) RNN_DOTC(1) RNN_DOTC(2) RNN_DOTC(3)                            \
    /* stage A: XOR15, keep idx bit2 == s8 */                                  \
    float rA0 = s8 ? a0 : a4, rA1 = s8 ? a1 : a5;                              \
    float rA2 = s8 ? a2 : a6, rA3 = s8 ? a3 : a7;                              \
    float b0 = (s8 ? a4 : a0) + dpp_mov<0x140>(rA0);                           \
    float b1 = (s8 ? a5 : a1) + dpp_mov<0x140>(rA1);                           \
    float b2 = (s8 ? a6 : a2) + dpp_mov<0x140>(rA2);                           \
    float b3 = (s8 ? a7 : a3) + dpp_mov<0x140>(rA3);                           \
    /* stage B: XOR7, keep idx bit1 == s4 */                                   \
    float rB0 = s4 ? b0 : b2, rB1 = s4 ? b1 : b3;                              \
    float c0 = (s4 ? b2 : b0) + dpp_mov<0x141>(rB0);                           \
    float c1 = (s4 ? b3 : b1) + dpp_mov<0x141>(rB1);                           \
    /* stage C: XOR2, keep idx bit0 == s2 */                                   \
    float rC = s2 ? c0 : c1;                                                   \
    float dd = (s2 ? c1 : c0) + dpp_mov<0x4E>(rC);                             \
    /* stage D: XOR1 all-reduce */                                             \
    float fin = dd + dpp_mov<0xB1>(dd);                                        \
    float y = fmaxf(fin + (XQ), 0.f);                                          \
    outp[(long)t * HID] = y;                                                   \
    *(half_t*)(hraw[((U) & 1) ^ 1] + hwb) = (half_t)y;                         \
    XQ = xnew;                                                                 \
    RNN_BAR();                                                                 \
  }

__global__ __launch_bounds__(512, 1) void rnn_kernel(
    const float* __restrict__ Whh, float* __restrict__ out, int T)
{
  // 16 chunks x (32B data + 16B pad) = 768 B, double buffered
  __shared__ alignas(128) unsigned char hraw[2][16 * 48];

  const int tid = threadIdx.x;
  const int l   = tid & 63;
  const int w   = tid >> 6;                // wave 0..7
  const int g   = l & 15;                  // K-chunk: columns [16g, 16g+16)
  const int o   = w * 4 + (l >> 4);        // output octet id (0..31)
  const int j0  = o * 8;                   // partial rows [j0, j0+8)
  const int rb  = g * 48;                  // LDS read base (bytes)
  const int jown = j0 + ((l >> 1) & 7);    // output row OWNED post-reduce
  const int hwb = ((jown >> 4) * 48 + (jown & 15) * 2);  // LDS write byte
  const bool s8 = (l & 8) != 0;
  const bool s4 = (l & 4) != 0;
  const bool s2 = (l & 2) != 0;
  float* outp = out + (long)blockIdx.x * SEQT * HID + jown;

  // W_hh[j0+i][16g + 8s .. +8] -> w8[i][s]  (64 VGPRs, static indexing)
  half8_t w8[8][2];
  #pragma unroll
  for (int i = 0; i < 8; ++i) {
    const float* wr = Whh + (long)(j0 + i) * HID + g * 16;
    #pragma unroll
    for (int s = 0; s < 2; ++s) {
      float4_t v0 = *(const float4_t*)(wr + s * 8);
      float4_t v1 = *(const float4_t*)(wr + s * 8 + 4);
      w8[i][s] = cvt8(v0, v1);
    }
  }

  // h_0 = 0 (covers data+pads of buffer 0: 768 B = 192 f32)
  if (tid < 192) ((float*)hraw[0])[tid] = 0.f;

  // 4-deep xp prefetch (named registers -> static indexing), all lanes
  float xq0 = outp[0L * HID];
  float xq1 = outp[1L * HID];
  float xq2 = outp[2L * HID];
  float xq3 = outp[3L * HID];
  RNN_BAR();

  #pragma unroll 1
  for (int t4 = 0; t4 < T; t4 += 4) {
    RNN_STEP(0, xq0)
    RNN_STEP(1, xq1)
    RNN_STEP(2, xq2)
    RNN_STEP(3, xq3)
  }
}

extern "C" void kernel_launch(void* const* d_in, const int* in_sizes, int n_in,
                              void* d_out, int out_size, void* d_ws, size_t ws_size,
                              hipStream_t stream) {
  const float* x   = (const float*)d_in[0];
  const float* Wxh = (const float*)d_in[1];
  const float* Whh = (const float*)d_in[2];
  const float* bh  = (const float*)d_in[3];
  float* out = (float*)d_out;

  if (ws_size >= (size_t)(DIM * HID * sizeof(half_t))) {
    half_t* Wh = (half_t*)d_ws;
    cvt_w_kernel<<<dim3((DIM * HID) / 1024), dim3(256), 0, stream>>>(Wxh, Wh);
    xproj_f16_v2<<<dim3((BATCH * SEQT) / 128), dim3(256), 0, stream>>>(x, Wh, bh, out);
  } else {
    xproj_kernel<<<dim3((BATCH * SEQT) / 64), dim3(256), 0, stream>>>(x, Wxh, bh, out);
  }
  rnn_kernel<<<dim3(BATCH), dim3(512), 0, stream>>>(Whh, out, SEQT);
}